// Round 1
// baseline (219.025 us; speedup 1.0000x reference)
//
#include <hip/hip_runtime.h>

typedef unsigned short u16;
typedef __attribute__((ext_vector_type(8))) short short8;
typedef __attribute__((ext_vector_type(4))) float f32x4;

#define GLL16(g, l) __builtin_amdgcn_global_load_lds(                         \
    (const __attribute__((address_space(1))) void*)(g),                        \
    (__attribute__((address_space(3))) void*)(l), 16, 0, 0)

__device__ __forceinline__ u16 f2bf(float f) {
  union { float f; unsigned u; } v; v.f = f;
  unsigned u = v.u;
  return (u16)((u + 0x7FFFu + ((u >> 16) & 1u)) >> 16);  // RNE
}

// ---------------------------------------------------------------------------
// Kernel A: convert x -> bf16, compute fp32 router logits (W_router in LDS).
// grid 512 x block 512 (8 waves). Each wave: 2 tokens. 64KB LDS -> 2 blk/CU.
// ---------------------------------------------------------------------------
__global__ __launch_bounds__(512) void k_conv_router(
    const float* __restrict__ x, const float* __restrict__ Wr,
    u16* __restrict__ xbf, float* __restrict__ logits)
{
  __shared__ float wlds[16384];  // 8 x 2048 fp32 = 64 KB
  {
    const float4* src = (const float4*)Wr;
    float4* dst = (float4*)wlds;
    int t = threadIdx.x;
#pragma unroll
    for (int i = 0; i < 8; ++i) dst[t + i * 512] = src[t + i * 512];
  }
  __syncthreads();
  int wave = threadIdx.x >> 6, lane = threadIdx.x & 63;
#pragma unroll 1
  for (int s = 0; s < 2; ++s) {
    int tok = blockIdx.x * 16 + wave * 2 + s;
    const float4* xrow = (const float4*)(x + tok * 2048);
    float4 xv[8];
#pragma unroll
    for (int i = 0; i < 8; ++i) xv[i] = xrow[lane + i * 64];
    ushort4* orow = (ushort4*)(xbf + tok * 2048);
#pragma unroll
    for (int i = 0; i < 8; ++i) {
      ushort4 o;
      o.x = f2bf(xv[i].x); o.y = f2bf(xv[i].y);
      o.z = f2bf(xv[i].z); o.w = f2bf(xv[i].w);
      orow[lane + i * 64] = o;
    }
    float acc[8];
#pragma unroll
    for (int e = 0; e < 8; ++e) acc[e] = 0.f;
#pragma unroll
    for (int e = 0; e < 8; ++e) {
      const float4* wrow = (const float4*)(wlds + e * 2048);
#pragma unroll
      for (int i = 0; i < 8; ++i) {
        float4 b = wrow[lane + i * 64];
        acc[e] += xv[i].x * b.x + xv[i].y * b.y + xv[i].z * b.z + xv[i].w * b.w;
      }
    }
#pragma unroll
    for (int e = 0; e < 8; ++e) {
      float v = acc[e];
#pragma unroll
      for (int off = 32; off > 0; off >>= 1) v += __shfl_xor(v, off, 64);
      acc[e] = v;
    }
    if (lane == 0) {
#pragma unroll
      for (int e = 0; e < 8; ++e) logits[tok * 8 + e] = acc[e];
    }
  }
}

// ---------------------------------------------------------------------------
// Kernel B: W_base->bf16 (blocks 0..1023), A_w->bf16 [64][2048] (1024..1055),
// B_w [8][2048][8] -> BmatT [2048][64] bf16 (1056..1063).
// ---------------------------------------------------------------------------
__global__ __launch_bounds__(256) void k_convert(
    const float* __restrict__ Wb, const float* __restrict__ Aw,
    const float* __restrict__ Bw,
    u16* __restrict__ wbf, u16* __restrict__ aabf, u16* __restrict__ bmt)
{
  int b = blockIdx.x, t = threadIdx.x;
  if (b < 1024) {
    int tid = b * 256 + t;
    const float4* src = (const float4*)Wb;
    ushort4* dst = (ushort4*)wbf;
#pragma unroll
    for (int i = 0; i < 4; ++i) {
      float4 v = src[tid + i * 262144];
      ushort4 o; o.x = f2bf(v.x); o.y = f2bf(v.y); o.z = f2bf(v.z); o.w = f2bf(v.w);
      dst[tid + i * 262144] = o;
    }
  } else if (b < 1056) {
    int tid = (b - 1024) * 256 + t;
    const float4* src = (const float4*)Aw;
    ushort4* dst = (ushort4*)aabf;
#pragma unroll
    for (int i = 0; i < 4; ++i) {
      float4 v = src[tid + i * 8192];
      ushort4 o; o.x = f2bf(v.x); o.y = f2bf(v.y); o.z = f2bf(v.z); o.w = f2bf(v.w);
      dst[tid + i * 8192] = o;
    }
  } else {
    int n = (b - 1056) * 256 + t;  // 0..2047
#pragma unroll
    for (int e = 0; e < 8; ++e) {
      const float4* src = (const float4*)(Bw + e * 16384 + n * 8);
      float4 v0 = src[0], v1 = src[1];
      ushort4 o0, o1;
      o0.x = f2bf(v0.x); o0.y = f2bf(v0.y); o0.z = f2bf(v0.z); o0.w = f2bf(v0.w);
      o1.x = f2bf(v1.x); o1.y = f2bf(v1.y); o1.z = f2bf(v1.z); o1.w = f2bf(v1.w);
      ushort4* dst = (ushort4*)(bmt + n * 64 + e * 8);
      dst[0] = o0; dst[1] = o1;
    }
  }
}

// ---------------------------------------------------------------------------
// Kernel C: h partials. h_all[m][64] = x_bf16 @ A_all^T, split-K (8 slices).
// grid (32 m-tiles of 256, 8 k-slices), 256 thr (4 waves, 64 rows each).
// ---------------------------------------------------------------------------
__global__ __launch_bounds__(256) void k_hgemm(
    const u16* __restrict__ xbf, const u16* __restrict__ aabf,
    float* __restrict__ P)
{
  __shared__ u16 As[256 * 64];
  __shared__ u16 Bs[64 * 64];
  int t = threadIdx.x, wave = t >> 6, lane = t & 63;
  int mBase = blockIdx.x * 256;
  int ks = blockIdx.y;
  int fr = lane & 15, fg = lane >> 4;
  int lrow = lane >> 3, lcol = (lane & 7) * 8;
  f32x4 zero = {0.f, 0.f, 0.f, 0.f};
  f32x4 acc[4][4];
#pragma unroll
  for (int i = 0; i < 4; ++i)
#pragma unroll
    for (int j = 0; j < 4; ++j) acc[i][j] = zero;
#pragma unroll 1
  for (int it = 0; it < 4; ++it) {
    int k0 = ks * 256 + it * 64;
    __syncthreads();
#pragma unroll
    for (int cc = 0; cc < 8; ++cc) {
      int c = wave * 8 + cc;
      GLL16(xbf + (mBase + c * 8 + lrow) * 2048 + k0 + lcol, &As[c * 512]);
    }
#pragma unroll
    for (int cc = 0; cc < 2; ++cc) {
      int c = wave * 2 + cc;
      GLL16(aabf + (c * 8 + lrow) * 2048 + k0 + lcol, &Bs[c * 512]);
    }
    __syncthreads();
#pragma unroll
    for (int kk = 0; kk < 2; ++kk) {
      short8 a[4], bfr[4];
#pragma unroll
      for (int i = 0; i < 4; ++i)
        a[i] = *(const short8*)&As[(wave * 64 + i * 16 + fr) * 64 + kk * 32 + fg * 8];
#pragma unroll
      for (int j = 0; j < 4; ++j)
        bfr[j] = *(const short8*)&Bs[(j * 16 + fr) * 64 + kk * 32 + fg * 8];
#pragma unroll
      for (int i = 0; i < 4; ++i)
#pragma unroll
        for (int j = 0; j < 4; ++j)
          acc[i][j] = __builtin_amdgcn_mfma_f32_16x16x32_bf16(a[i], bfr[j], acc[i][j], 0, 0, 0);
    }
  }
#pragma unroll
  for (int i = 0; i < 4; ++i)
#pragma unroll
    for (int j = 0; j < 4; ++j)
#pragma unroll
      for (int r = 0; r < 4; ++r) {
        int m = mBase + wave * 64 + i * 16 + fg * 4 + r;
        int n = j * 16 + fr;
        P[(ks * 8192 + m) * 64 + n] = acc[i][j][r];
      }
}

// ---------------------------------------------------------------------------
// Kernel D: one wave per token. top-2 (first-index ties, = jax.lax.top_k),
// softmax gates, reduce 8 K-slice partials, emit sparse G[8192][64] bf16.
// ---------------------------------------------------------------------------
__global__ __launch_bounds__(256) void k_topk(
    const float* __restrict__ logits, const float* __restrict__ P,
    u16* __restrict__ G)
{
  int t = threadIdx.x, wave = t >> 6, lane = t & 63;
  int tok = blockIdx.x * 4 + wave;
  const float* lg = logits + tok * 8;
  float la[8];
#pragma unroll
  for (int e = 0; e < 8; ++e) la[e] = lg[e];
  float v0 = la[0]; int i0 = 0;
#pragma unroll
  for (int e = 1; e < 8; ++e) { if (la[e] > v0) { v0 = la[e]; i0 = e; } }
  float v1 = -3.4e38f; int i1 = 0;
#pragma unroll
  for (int e = 0; e < 8; ++e) { if (e != i0 && la[e] > v1) { v1 = la[e]; i1 = e; } }
  float ex = expf(v1 - v0);
  float inv = 1.f / (1.f + ex);
  float gate0 = inv, gate1 = ex * inv;
  int e = lane >> 3;
  float h = 0.f;
#pragma unroll
  for (int ks = 0; ks < 8; ++ks) h += P[(ks * 8192 + tok) * 64 + lane];
  float g = (e == i0) ? gate0 : ((e == i1) ? gate1 : 0.f);
  G[tok * 64 + lane] = f2bf(2.0f * g * h);  // SCALE = alpha/r = 2
}

// ---------------------------------------------------------------------------
// Kernel E: main GEMM, 128x128 tile, BK=64, K=2048 (+64 virtual K for LoRA:
// A-side = G, B-side = BmatT). Epilogue adds bias only.
// ---------------------------------------------------------------------------
__global__ __launch_bounds__(256) void k_main(
    const u16* __restrict__ xbf, const u16* __restrict__ wbf,
    const u16* __restrict__ G, const u16* __restrict__ BmT,
    const float* __restrict__ bias, float* __restrict__ out)
{
  __shared__ u16 As[128 * 64];
  __shared__ u16 Bs[128 * 64];
  int t = threadIdx.x, wave = t >> 6, lane = t & 63;
  int wr = wave >> 1, wc = wave & 1;
  int mBase = blockIdx.x * 128, nBase = blockIdx.y * 128;
  int fr = lane & 15, fg = lane >> 4;
  int lrow = lane >> 3, lcol = (lane & 7) * 8;
  f32x4 zero = {0.f, 0.f, 0.f, 0.f};
  f32x4 acc[4][4];
#pragma unroll
  for (int i = 0; i < 4; ++i)
#pragma unroll
    for (int j = 0; j < 4; ++j) acc[i][j] = zero;
#pragma unroll 1
  for (int kt = 0; kt < 33; ++kt) {
    const u16* aS; const u16* bS; int lda, ldb, k0;
    if (kt < 32) { aS = xbf; bS = wbf; lda = 2048; ldb = 2048; k0 = kt * 64; }
    else         { aS = G;   bS = BmT; lda = 64;   ldb = 64;   k0 = 0; }
    __syncthreads();
#pragma unroll
    for (int cc = 0; cc < 4; ++cc) {
      int c = wave * 4 + cc;
      GLL16(aS + (mBase + c * 8 + lrow) * lda + k0 + lcol, &As[c * 512]);
      GLL16(bS + (nBase + c * 8 + lrow) * ldb + k0 + lcol, &Bs[c * 512]);
    }
    __syncthreads();
#pragma unroll
    for (int kk = 0; kk < 2; ++kk) {
      short8 a[4], b[4];
#pragma unroll
      for (int i = 0; i < 4; ++i)
        a[i] = *(const short8*)&As[(wr * 64 + i * 16 + fr) * 64 + kk * 32 + fg * 8];
#pragma unroll
      for (int j = 0; j < 4; ++j)
        b[j] = *(const short8*)&Bs[(wc * 64 + j * 16 + fr) * 64 + kk * 32 + fg * 8];
#pragma unroll
      for (int i = 0; i < 4; ++i)
#pragma unroll
        for (int j = 0; j < 4; ++j)
          acc[i][j] = __builtin_amdgcn_mfma_f32_16x16x32_bf16(a[i], b[j], acc[i][j], 0, 0, 0);
    }
  }
#pragma unroll
  for (int j = 0; j < 4; ++j) {
    int n = nBase + wc * 64 + j * 16 + fr;
    float bv = bias[n];
#pragma unroll
    for (int i = 0; i < 4; ++i) {
#pragma unroll
      for (int r = 0; r < 4; ++r) {
        int m = mBase + wr * 64 + i * 16 + fg * 4 + r;
        out[m * 2048 + n] = acc[i][j][r] + bv;
      }
    }
  }
}

// ---------------------------------------------------------------------------
extern "C" void kernel_launch(void* const* d_in, const int* in_sizes, int n_in,
                              void* d_out, int out_size, void* d_ws, size_t ws_size,
                              hipStream_t stream) {
  const float* x  = (const float*)d_in[0];   // [4,2048,2048]
  const float* Wb = (const float*)d_in[1];   // [2048,2048]
  const float* bb = (const float*)d_in[2];   // [2048]
  const float* Wr = (const float*)d_in[3];   // [8,2048]
  const float* Aw = (const float*)d_in[4];   // [8,8,2048] == [64][2048]
  const float* Bw = (const float*)d_in[5];   // [8,2048,8]

  char* ws = (char*)d_ws;                    // ~43.8 MB used
  u16*   xbf  = (u16*)  (ws + 0);            // 33,554,432 B
  u16*   wbf  = (u16*)  (ws + 33554432);     //  8,388,608 B
  u16*   aabf = (u16*)  (ws + 41943040);     //    262,144 B
  u16*   bmt  = (u16*)  (ws + 42205184);     //    262,144 B
  float* lgt  = (float*)(ws + 42467328);     //    262,144 B
  u16*   G    = (u16*)  (ws + 42729472);     //  1,048,576 B
  // h-partials [8][8192][64] f32 (16.7 MB) live in d_out; fully consumed by
  // k_topk before k_main overwrites all of d_out. Same-stream ordering.
  float* P   = (float*)d_out;
  float* out = (float*)d_out;

  hipLaunchKernelGGL(k_conv_router, dim3(512),     dim3(512), 0, stream, x, Wr, xbf, lgt);
  hipLaunchKernelGGL(k_convert,     dim3(1064),    dim3(256), 0, stream, Wb, Aw, Bw, wbf, aabf, bmt);
  hipLaunchKernelGGL(k_hgemm,       dim3(32, 8),   dim3(256), 0, stream, xbf, aabf, P);
  hipLaunchKernelGGL(k_topk,        dim3(2048),    dim3(256), 0, stream, lgt, P, G);
  hipLaunchKernelGGL(k_main,        dim3(64, 16),  dim3(256), 0, stream, xbf, wbf, G, bmt, bb, out);
}

// Round 2
// 191.300 us; speedup vs baseline: 1.1449x; 1.1449x over previous
//
#include <hip/hip_runtime.h>

typedef unsigned short u16;
typedef __attribute__((ext_vector_type(8))) short short8;
typedef __attribute__((ext_vector_type(4))) float f32x4;

#define GLL16(g, l) __builtin_amdgcn_global_load_lds(                         \
    (const __attribute__((address_space(1))) void*)(g),                        \
    (__attribute__((address_space(3))) void*)(l), 16, 0, 0)

__device__ __forceinline__ u16 f2bf(float f) {
  union { float f; unsigned u; } v; v.f = f;
  unsigned u = v.u;
  return (u16)((u + 0x7FFFu + ((u >> 16) & 1u)) >> 16);  // RNE
}

// ---------------------------------------------------------------------------
// Kernel A: convert x -> bf16, compute fp32 router logits (W_router in LDS).
// ---------------------------------------------------------------------------
__global__ __launch_bounds__(512) void k_conv_router(
    const float* __restrict__ x, const float* __restrict__ Wr,
    u16* __restrict__ xbf, float* __restrict__ logits)
{
  __shared__ float wlds[16384];  // 8 x 2048 fp32 = 64 KB
  {
    const float4* src = (const float4*)Wr;
    float4* dst = (float4*)wlds;
    int t = threadIdx.x;
#pragma unroll
    for (int i = 0; i < 8; ++i) dst[t + i * 512] = src[t + i * 512];
  }
  __syncthreads();
  int wave = threadIdx.x >> 6, lane = threadIdx.x & 63;
#pragma unroll 1
  for (int s = 0; s < 2; ++s) {
    int tok = blockIdx.x * 16 + wave * 2 + s;
    const float4* xrow = (const float4*)(x + tok * 2048);
    float4 xv[8];
#pragma unroll
    for (int i = 0; i < 8; ++i) xv[i] = xrow[lane + i * 64];
    ushort4* orow = (ushort4*)(xbf + tok * 2048);
#pragma unroll
    for (int i = 0; i < 8; ++i) {
      ushort4 o;
      o.x = f2bf(xv[i].x); o.y = f2bf(xv[i].y);
      o.z = f2bf(xv[i].z); o.w = f2bf(xv[i].w);
      orow[lane + i * 64] = o;
    }
    float acc[8];
#pragma unroll
    for (int e = 0; e < 8; ++e) acc[e] = 0.f;
#pragma unroll
    for (int e = 0; e < 8; ++e) {
      const float4* wrow = (const float4*)(wlds + e * 2048);
#pragma unroll
      for (int i = 0; i < 8; ++i) {
        float4 b = wrow[lane + i * 64];
        acc[e] += xv[i].x * b.x + xv[i].y * b.y + xv[i].z * b.z + xv[i].w * b.w;
      }
    }
#pragma unroll
    for (int e = 0; e < 8; ++e) {
      float v = acc[e];
#pragma unroll
      for (int off = 32; off > 0; off >>= 1) v += __shfl_xor(v, off, 64);
      acc[e] = v;
    }
    if (lane == 0) {
#pragma unroll
      for (int e = 0; e < 8; ++e) logits[tok * 8 + e] = acc[e];
    }
  }
}

// ---------------------------------------------------------------------------
// Kernel B: W_base->bf16, A_w->bf16, B_w -> BmatT [2048][64] bf16.
// ---------------------------------------------------------------------------
__global__ __launch_bounds__(256) void k_convert(
    const float* __restrict__ Wb, const float* __restrict__ Aw,
    const float* __restrict__ Bw,
    u16* __restrict__ wbf, u16* __restrict__ aabf, u16* __restrict__ bmt)
{
  int b = blockIdx.x, t = threadIdx.x;
  if (b < 1024) {
    int tid = b * 256 + t;
    const float4* src = (const float4*)Wb;
    ushort4* dst = (ushort4*)wbf;
#pragma unroll
    for (int i = 0; i < 4; ++i) {
      float4 v = src[tid + i * 262144];
      ushort4 o; o.x = f2bf(v.x); o.y = f2bf(v.y); o.z = f2bf(v.z); o.w = f2bf(v.w);
      dst[tid + i * 262144] = o;
    }
  } else if (b < 1056) {
    int tid = (b - 1024) * 256 + t;
    const float4* src = (const float4*)Aw;
    ushort4* dst = (ushort4*)aabf;
#pragma unroll
    for (int i = 0; i < 4; ++i) {
      float4 v = src[tid + i * 8192];
      ushort4 o; o.x = f2bf(v.x); o.y = f2bf(v.y); o.z = f2bf(v.z); o.w = f2bf(v.w);
      dst[tid + i * 8192] = o;
    }
  } else {
    int n = (b - 1056) * 256 + t;  // 0..2047
#pragma unroll
    for (int e = 0; e < 8; ++e) {
      const float4* src = (const float4*)(Bw + e * 16384 + n * 8);
      float4 v0 = src[0], v1 = src[1];
      ushort4 o0, o1;
      o0.x = f2bf(v0.x); o0.y = f2bf(v0.y); o0.z = f2bf(v0.z); o0.w = f2bf(v0.w);
      o1.x = f2bf(v1.x); o1.y = f2bf(v1.y); o1.z = f2bf(v1.z); o1.w = f2bf(v1.w);
      ushort4* dst = (ushort4*)(bmt + n * 64 + e * 8);
      dst[0] = o0; dst[1] = o1;
    }
  }
}

// ---------------------------------------------------------------------------
// Kernel C: h partials. h_all[m][64] = x_bf16 @ A_all^T, split-K (8 slices).
// ---------------------------------------------------------------------------
__global__ __launch_bounds__(256) void k_hgemm(
    const u16* __restrict__ xbf, const u16* __restrict__ aabf,
    float* __restrict__ P)
{
  __shared__ u16 As[256 * 64];
  __shared__ u16 Bs[64 * 64];
  int t = threadIdx.x, wave = t >> 6, lane = t & 63;
  int mBase = blockIdx.x * 256;
  int ks = blockIdx.y;
  int fr = lane & 15, fg = lane >> 4;
  int lrow = lane >> 3, lcol = (lane & 7) * 8;
  f32x4 zero = {0.f, 0.f, 0.f, 0.f};
  f32x4 acc[4][4];
#pragma unroll
  for (int i = 0; i < 4; ++i)
#pragma unroll
    for (int j = 0; j < 4; ++j) acc[i][j] = zero;
#pragma unroll 1
  for (int it = 0; it < 4; ++it) {
    int k0 = ks * 256 + it * 64;
    __syncthreads();
#pragma unroll
    for (int cc = 0; cc < 8; ++cc) {
      int c = wave * 8 + cc;
      GLL16(xbf + (mBase + c * 8 + lrow) * 2048 + k0 + lcol, &As[c * 512]);
    }
#pragma unroll
    for (int cc = 0; cc < 2; ++cc) {
      int c = wave * 2 + cc;
      GLL16(aabf + (c * 8 + lrow) * 2048 + k0 + lcol, &Bs[c * 512]);
    }
    __syncthreads();
#pragma unroll
    for (int kk = 0; kk < 2; ++kk) {
      short8 a[4], bfr[4];
#pragma unroll
      for (int i = 0; i < 4; ++i)
        a[i] = *(const short8*)&As[(wave * 64 + i * 16 + fr) * 64 + kk * 32 + fg * 8];
#pragma unroll
      for (int j = 0; j < 4; ++j)
        bfr[j] = *(const short8*)&Bs[(j * 16 + fr) * 64 + kk * 32 + fg * 8];
#pragma unroll
      for (int i = 0; i < 4; ++i)
#pragma unroll
        for (int j = 0; j < 4; ++j)
          acc[i][j] = __builtin_amdgcn_mfma_f32_16x16x32_bf16(a[i], bfr[j], acc[i][j], 0, 0, 0);
    }
  }
#pragma unroll
  for (int i = 0; i < 4; ++i)
#pragma unroll
    for (int j = 0; j < 4; ++j)
#pragma unroll
      for (int r = 0; r < 4; ++r) {
        int m = mBase + wave * 64 + i * 16 + fg * 4 + r;
        int n = j * 16 + fr;
        P[(ks * 8192 + m) * 64 + n] = acc[i][j][r];
      }
}

// ---------------------------------------------------------------------------
// Kernel D: per-token top-2 + softmax gates; reduce split-K partials; emit
// sparse gate-scaled G[8192][64] bf16.
// ---------------------------------------------------------------------------
__global__ __launch_bounds__(256) void k_topk(
    const float* __restrict__ logits, const float* __restrict__ P,
    u16* __restrict__ G)
{
  int t = threadIdx.x, wave = t >> 6, lane = t & 63;
  int tok = blockIdx.x * 4 + wave;
  const float* lg = logits + tok * 8;
  float la[8];
#pragma unroll
  for (int e = 0; e < 8; ++e) la[e] = lg[e];
  float v0 = la[0]; int i0 = 0;
#pragma unroll
  for (int e = 1; e < 8; ++e) { if (la[e] > v0) { v0 = la[e]; i0 = e; } }
  float v1 = -3.4e38f; int i1 = 0;
#pragma unroll
  for (int e = 0; e < 8; ++e) { if (e != i0 && la[e] > v1) { v1 = la[e]; i1 = e; } }
  float ex = expf(v1 - v0);
  float inv = 1.f / (1.f + ex);
  float gate0 = inv, gate1 = ex * inv;
  int e = lane >> 3;
  float h = 0.f;
#pragma unroll
  for (int ks = 0; ks < 8; ++ks) h += P[(ks * 8192 + tok) * 64 + lane];
  float g = (e == i0) ? gate0 : ((e == i1) ? gate1 : 0.f);
  G[tok * 64 + lane] = f2bf(2.0f * g * h);  // SCALE = alpha/r = 2
}

// ---------------------------------------------------------------------------
// Kernel E: main GEMM, 256x256 tile, BK=64, 8-phase schedule (T1-T5).
// K = 2048 (tiles 0..31) + virtual LoRA K-tile 32 (A=G, B=BmT, ld=64).
// 8 waves (2M x 4N), per-wave C = 128x64. 128 KiB LDS, double-buffered,
// st-swizzled (XOR involution applied on global src AND ds_read; LDS dest
// linear per global_load_lds constraint).
// Per K-tile phases: p0 {rd A mi0-7 + B nj0-1 | stage (t+1).Bhi | MFMA nj0}
//                    p1 {rd B nj2-3           | stage (t+2).Alo | MFMA nj1}
//                    p2 {                       stage (t+2).Blo | MFMA nj2}
//                    p3 {                       stage (t+2).Ahi | MFMA nj3}
// A-buf(t) fully read at p0-end, B-buf(t) at p1-end -> every stage targets a
// consumed region (lgkmcnt(0)+barrier ordering). vmcnt(6) at tile end leaves
// exactly t+2's 3 newest half-tiles in flight => tile t+1 fully landed.
// ---------------------------------------------------------------------------
__global__ __launch_bounds__(512, 2) void k_main(
    const u16* __restrict__ xbf, const u16* __restrict__ wbf,
    const u16* __restrict__ G, const u16* __restrict__ BmT,
    const float* __restrict__ bias, float* __restrict__ out)
{
  __shared__ u16 lds[65536];  // A bufs: [0,32768)  B bufs: [32768,65536)
  const int tid = threadIdx.x;
  const int w = tid >> 6, lane = tid & 63;
  const int fr = lane & 15, fg = lane >> 4;
  const int wr = w >> 2, wc = w & 3;

  // XCD-aware swizzle (256 blocks, 256%8==0 -> bijective)
  const int b0 = blockIdx.x;
  const int wg = (b0 & 7) * 32 + (b0 >> 3);
  const int mBase = (wg >> 3) * 256;   // 32 m-tiles
  const int nBase = (wg & 7) * 256;    //  8 n-tiles

  // staging addressing (linear LDS dest; swizzled global source col)
  const int rl = lane >> 3;                 // 0..7
  const int ce = ((lane & 7) ^ rl) << 3;    // source col elems (XOR swizzle)
  // ds_read addressing (same XOR involution)
  const int swz = (fr & 7) << 3;
  const int colk0 = (fg * 8) ^ swz;
  const int colk1 = (32 + fg * 8) ^ swz;
  const int aOff = (wr * 128 + fr) * 64;
  const int bOff = (wc * 64 + fr) * 64;

  f32x4 acc[8][4];
  const f32x4 zero = {0.f, 0.f, 0.f, 0.f};
#pragma unroll
  for (int mi = 0; mi < 8; ++mi)
#pragma unroll
    for (int nj = 0; nj < 4; ++nj) acc[mi][nj] = zero;

  // half codes: 0=A.lo 1=A.hi 2=B.lo 3=B.hi
  auto STAGE = [&](int s, int which) {
    if (s > 32) return;
    const bool isA = (which < 2);
    const int h = which & 1;
    const u16* src; int ld, k0;
    if (s < 32) { src = isA ? xbf : wbf; ld = 2048; k0 = s * 64; }
    else        { src = isA ? G   : BmT; ld = 64;   k0 = 0;      }
    const int rb = (isA ? mBase : nBase) + h * 128 + w * 8 + rl;
    u16* dst = lds + (isA ? 0 : 32768) + (s & 1) * 16384 + h * 8192 + w * 512;
    GLL16(src + rb * ld + k0 + ce, dst);            // rows rb.. (q=0)
    GLL16(src + (rb + 64) * ld + k0 + ce, dst + 4096);  // rows rb+64.. (q=1)
  };

#define MFMA_BURST(NJ)                                                        \
  __builtin_amdgcn_s_setprio(1);                                              \
  _Pragma("unroll")                                                           \
  for (int kk = 0; kk < 2; ++kk) {                                            \
    _Pragma("unroll")                                                         \
    for (int mi = 0; mi < 8; ++mi)                                            \
      acc[mi][NJ] = __builtin_amdgcn_mfma_f32_16x16x32_bf16(                  \
          a[mi][kk], bb[NJ][kk], acc[mi][NJ], 0, 0, 0);                       \
  }                                                                           \
  __builtin_amdgcn_s_setprio(0);

  // ---- prologue: tile0 all 4 halves + tile1 {A.lo, B.lo, A.hi}
  STAGE(0, 0); STAGE(0, 1); STAGE(0, 2); STAGE(0, 3);
  STAGE(1, 0); STAGE(1, 2); STAGE(1, 1);
  asm volatile("s_waitcnt vmcnt(6)" ::: "memory");
  __builtin_amdgcn_s_barrier();

  short8 a[8][2], bb[4][2];
#pragma unroll 1
  for (int t = 0; t < 33; ++t) {
    const u16* Ab = lds + (t & 1) * 16384;
    const u16* Bb = lds + 32768 + (t & 1) * 16384;
    // ---- phase 0
#pragma unroll
    for (int mi = 0; mi < 8; ++mi) {
      a[mi][0] = *(const short8*)(Ab + aOff + mi * 1024 + colk0);
      a[mi][1] = *(const short8*)(Ab + aOff + mi * 1024 + colk1);
    }
#pragma unroll
    for (int nj = 0; nj < 2; ++nj) {
      bb[nj][0] = *(const short8*)(Bb + bOff + nj * 1024 + colk0);
      bb[nj][1] = *(const short8*)(Bb + bOff + nj * 1024 + colk1);
    }
    STAGE(t + 1, 3);
    __builtin_amdgcn_s_barrier();
    asm volatile("s_waitcnt lgkmcnt(0)" ::: "memory");
    MFMA_BURST(0)
    __builtin_amdgcn_s_barrier();
    // ---- phase 1
#pragma unroll
    for (int nj = 2; nj < 4; ++nj) {
      bb[nj][0] = *(const short8*)(Bb + bOff + nj * 1024 + colk0);
      bb[nj][1] = *(const short8*)(Bb + bOff + nj * 1024 + colk1);
    }
    STAGE(t + 2, 0);
    __builtin_amdgcn_s_barrier();
    asm volatile("s_waitcnt lgkmcnt(0)" ::: "memory");
    MFMA_BURST(1)
    __builtin_amdgcn_s_barrier();
    // ---- phase 2
    STAGE(t + 2, 2);
    __builtin_amdgcn_s_barrier();
    MFMA_BURST(2)
    __builtin_amdgcn_s_barrier();
    // ---- phase 3
    STAGE(t + 2, 1);
    __builtin_amdgcn_s_barrier();
    MFMA_BURST(3)
    if (t < 31)       { asm volatile("s_waitcnt vmcnt(6)" ::: "memory"); }
    else if (t == 31) { asm volatile("s_waitcnt vmcnt(0)" ::: "memory"); }
    __builtin_amdgcn_s_barrier();
  }

  // ---- epilogue: bias add + store
#pragma unroll
  for (int nj = 0; nj < 4; ++nj) {
    const int n = nBase + wc * 64 + nj * 16 + fr;
    const float bv = bias[n];
#pragma unroll
    for (int mi = 0; mi < 8; ++mi) {
      const int m = mBase + wr * 128 + mi * 16 + fg * 4;
#pragma unroll
      for (int r = 0; r < 4; ++r)
        out[(m + r) * 2048 + n] = acc[mi][nj][r] + bv;
    }
  }
#undef MFMA_BURST
}

// ---------------------------------------------------------------------------
extern "C" void kernel_launch(void* const* d_in, const int* in_sizes, int n_in,
                              void* d_out, int out_size, void* d_ws, size_t ws_size,
                              hipStream_t stream) {
  const float* x  = (const float*)d_in[0];   // [4,2048,2048]
  const float* Wb = (const float*)d_in[1];   // [2048,2048]
  const float* bb = (const float*)d_in[2];   // [2048]
  const float* Wr = (const float*)d_in[3];   // [8,2048]
  const float* Aw = (const float*)d_in[4];   // [8,8,2048] == [64][2048]
  const float* Bw = (const float*)d_in[5];   // [8,2048,8]

  char* ws = (char*)d_ws;
  u16*   xbf  = (u16*)  (ws + 0);            // 33,554,432 B
  u16*   wbf  = (u16*)  (ws + 33554432);     //  8,388,608 B
  u16*   aabf = (u16*)  (ws + 41943040);     //    262,144 B
  u16*   bmt  = (u16*)  (ws + 42205184);     //    262,144 B
  float* lgt  = (float*)(ws + 42467328);     //    262,144 B
  u16*   G    = (u16*)  (ws + 42729472);     //  1,048,576 B
  // h-partials [8][8192][64] f32 live in d_out; fully consumed by k_topk
  // before k_main overwrites all of d_out. Same-stream ordering.
  float* P   = (float*)d_out;
  float* out = (float*)d_out;

  hipLaunchKernelGGL(k_conv_router, dim3(512),    dim3(512), 0, stream, x, Wr, xbf, lgt);
  hipLaunchKernelGGL(k_convert,     dim3(1064),   dim3(256), 0, stream, Wb, Aw, Bw, wbf, aabf, bmt);
  hipLaunchKernelGGL(k_hgemm,       dim3(32, 8),  dim3(256), 0, stream, xbf, aabf, P);
  hipLaunchKernelGGL(k_topk,        dim3(2048),   dim3(256), 0, stream, lgt, P, G);
  hipLaunchKernelGGL(k_main,        dim3(256),    dim3(512), 0, stream, xbf, wbf, G, bmt, bb, out);
}

// Round 3
// 126.988 us; speedup vs baseline: 1.7248x; 1.5064x over previous
//
#include <hip/hip_runtime.h>

typedef unsigned short u16;
typedef __attribute__((ext_vector_type(8))) short short8;
typedef __attribute__((ext_vector_type(4))) float f32x4;

#define GLL16(g, l) __builtin_amdgcn_global_load_lds(                         \
    (const __attribute__((address_space(1))) void*)(g),                        \
    (__attribute__((address_space(3))) void*)(l), 16, 0, 0)

__device__ __forceinline__ u16 f2bf(float f) {
  union { float f; unsigned u; } v; v.f = f;
  unsigned u = v.u;
  return (u16)((u + 0x7FFFu + ((u >> 16) & 1u)) >> 16);  // RNE
}

// ---------------------------------------------------------------------------
// Kernel A: convert x -> bf16, compute fp32 router logits (W_router in LDS).
// Chunk-interleaved: xv chunk is consumed (convert+store+all-8-expert FMA)
// before the next chunk loads -> no large live array -> no scratch spill.
// ---------------------------------------------------------------------------
__global__ __launch_bounds__(512) void k_conv_router(
    const float* __restrict__ x, const float* __restrict__ Wr,
    u16* __restrict__ xbf, float* __restrict__ logits)
{
  __shared__ float wlds[16384];  // 8 x 2048 fp32 = 64 KB
  {
    const float4* src = (const float4*)Wr;
    float4* dst = (float4*)wlds;
    int t = threadIdx.x;
#pragma unroll
    for (int i = 0; i < 8; ++i) dst[t + i * 512] = src[t + i * 512];
  }
  __syncthreads();
  int wave = threadIdx.x >> 6, lane = threadIdx.x & 63;
  const float4* wv = (const float4*)wlds;
#pragma unroll 1
  for (int s = 0; s < 2; ++s) {
    int tok = blockIdx.x * 16 + wave * 2 + s;
    const float4* xrow = (const float4*)(x + tok * 2048);
    ushort4* orow = (ushort4*)(xbf + tok * 2048);
    float acc[8];
#pragma unroll
    for (int e = 0; e < 8; ++e) acc[e] = 0.f;
#pragma unroll 1
    for (int i = 0; i < 8; ++i) {
      float4 xv = xrow[lane + i * 64];
      ushort4 o;
      o.x = f2bf(xv.x); o.y = f2bf(xv.y);
      o.z = f2bf(xv.z); o.w = f2bf(xv.w);
      orow[lane + i * 64] = o;
#pragma unroll
      for (int e = 0; e < 8; ++e) {
        float4 b = wv[e * 512 + lane + i * 64];
        acc[e] += xv.x * b.x + xv.y * b.y + xv.z * b.z + xv.w * b.w;
      }
    }
#pragma unroll
    for (int e = 0; e < 8; ++e) {
      float v = acc[e];
#pragma unroll
      for (int off = 32; off > 0; off >>= 1) v += __shfl_xor(v, off, 64);
      acc[e] = v;
    }
    if (lane == 0) {
#pragma unroll
      for (int e = 0; e < 8; ++e) logits[tok * 8 + e] = acc[e];
    }
  }
}

// ---------------------------------------------------------------------------
// Kernel B: W_base->bf16, A_w->bf16, B_w -> BmatT [2048][64] bf16.
// ---------------------------------------------------------------------------
__global__ __launch_bounds__(256) void k_convert(
    const float* __restrict__ Wb, const float* __restrict__ Aw,
    const float* __restrict__ Bw,
    u16* __restrict__ wbf, u16* __restrict__ aabf, u16* __restrict__ bmt)
{
  int b = blockIdx.x, t = threadIdx.x;
  if (b < 1024) {
    int tid = b * 256 + t;
    const float4* src = (const float4*)Wb;
    ushort4* dst = (ushort4*)wbf;
#pragma unroll
    for (int i = 0; i < 4; ++i) {
      float4 v = src[tid + i * 262144];
      ushort4 o; o.x = f2bf(v.x); o.y = f2bf(v.y); o.z = f2bf(v.z); o.w = f2bf(v.w);
      dst[tid + i * 262144] = o;
    }
  } else if (b < 1056) {
    int tid = (b - 1024) * 256 + t;
    const float4* src = (const float4*)Aw;
    ushort4* dst = (ushort4*)aabf;
#pragma unroll
    for (int i = 0; i < 4; ++i) {
      float4 v = src[tid + i * 8192];
      ushort4 o; o.x = f2bf(v.x); o.y = f2bf(v.y); o.z = f2bf(v.z); o.w = f2bf(v.w);
      dst[tid + i * 8192] = o;
    }
  } else {
    int n = (b - 1056) * 256 + t;  // 0..2047
#pragma unroll
    for (int e = 0; e < 8; ++e) {
      const float4* src = (const float4*)(Bw + e * 16384 + n * 8);
      float4 v0 = src[0], v1 = src[1];
      ushort4 o0, o1;
      o0.x = f2bf(v0.x); o0.y = f2bf(v0.y); o0.z = f2bf(v0.z); o0.w = f2bf(v0.w);
      o1.x = f2bf(v1.x); o1.y = f2bf(v1.y); o1.z = f2bf(v1.z); o1.w = f2bf(v1.w);
      ushort4* dst = (ushort4*)(bmt + n * 64 + e * 8);
      dst[0] = o0; dst[1] = o1;
    }
  }
}

// ---------------------------------------------------------------------------
// Kernel C: h partials. h_all[m][64] = x_bf16 @ A_all^T, split-K (8 slices).
// ---------------------------------------------------------------------------
__global__ __launch_bounds__(256) void k_hgemm(
    const u16* __restrict__ xbf, const u16* __restrict__ aabf,
    float* __restrict__ P)
{
  __shared__ u16 As[256 * 64];
  __shared__ u16 Bs[64 * 64];
  int t = threadIdx.x, wave = t >> 6, lane = t & 63;
  int mBase = blockIdx.x * 256;
  int ks = blockIdx.y;
  int fr = lane & 15, fg = lane >> 4;
  int lrow = lane >> 3, lcol = (lane & 7) * 8;
  f32x4 zero = {0.f, 0.f, 0.f, 0.f};
  f32x4 acc[4][4];
#pragma unroll
  for (int i = 0; i < 4; ++i)
#pragma unroll
    for (int j = 0; j < 4; ++j) acc[i][j] = zero;
#pragma unroll 1
  for (int it = 0; it < 4; ++it) {
    int k0 = ks * 256 + it * 64;
    __syncthreads();
#pragma unroll
    for (int cc = 0; cc < 8; ++cc) {
      int c = wave * 8 + cc;
      GLL16(xbf + (mBase + c * 8 + lrow) * 2048 + k0 + lcol, &As[c * 512]);
    }
#pragma unroll
    for (int cc = 0; cc < 2; ++cc) {
      int c = wave * 2 + cc;
      GLL16(aabf + (c * 8 + lrow) * 2048 + k0 + lcol, &Bs[c * 512]);
    }
    __syncthreads();
#pragma unroll
    for (int kk = 0; kk < 2; ++kk) {
      short8 a[4], bfr[4];
#pragma unroll
      for (int i = 0; i < 4; ++i)
        a[i] = *(const short8*)&As[(wave * 64 + i * 16 + fr) * 64 + kk * 32 + fg * 8];
#pragma unroll
      for (int j = 0; j < 4; ++j)
        bfr[j] = *(const short8*)&Bs[(j * 16 + fr) * 64 + kk * 32 + fg * 8];
#pragma unroll
      for (int i = 0; i < 4; ++i)
#pragma unroll
        for (int j = 0; j < 4; ++j)
          acc[i][j] = __builtin_amdgcn_mfma_f32_16x16x32_bf16(a[i], bfr[j], acc[i][j], 0, 0, 0);
    }
  }
#pragma unroll
  for (int i = 0; i < 4; ++i)
#pragma unroll
    for (int j = 0; j < 4; ++j)
#pragma unroll
      for (int r = 0; r < 4; ++r) {
        int m = mBase + wave * 64 + i * 16 + fg * 4 + r;
        int n = j * 16 + fr;
        P[(ks * 8192 + m) * 64 + n] = acc[i][j][r];
      }
}

// ---------------------------------------------------------------------------
// Kernel D: per-token top-2 + softmax gates; reduce split-K partials; emit
// sparse gate-scaled G[8192][64] bf16.
// ---------------------------------------------------------------------------
__global__ __launch_bounds__(256) void k_topk(
    const float* __restrict__ logits, const float* __restrict__ P,
    u16* __restrict__ G)
{
  int t = threadIdx.x, wave = t >> 6, lane = t & 63;
  int tok = blockIdx.x * 4 + wave;
  const float* lg = logits + tok * 8;
  float la[8];
#pragma unroll
  for (int e = 0; e < 8; ++e) la[e] = lg[e];
  float v0 = la[0]; int i0 = 0;
#pragma unroll
  for (int e = 1; e < 8; ++e) { if (la[e] > v0) { v0 = la[e]; i0 = e; } }
  float v1 = -3.4e38f; int i1 = 0;
#pragma unroll
  for (int e = 0; e < 8; ++e) { if (e != i0 && la[e] > v1) { v1 = la[e]; i1 = e; } }
  float ex = expf(v1 - v0);
  float inv = 1.f / (1.f + ex);
  float gate0 = inv, gate1 = ex * inv;
  int e = lane >> 3;
  float h = 0.f;
#pragma unroll
  for (int ks = 0; ks < 8; ++ks) h += P[(ks * 8192 + tok) * 64 + lane];
  float g = (e == i0) ? gate0 : ((e == i1) ? gate1 : 0.f);
  G[tok * 64 + lane] = f2bf(2.0f * g * h);  // SCALE = alpha/r = 2
}

// ---------------------------------------------------------------------------
// Kernel E: main GEMM, 256x256 tile, BK=64, 8-phase schedule (T1-T5).
// K = 2048 (tiles 0..31) + virtual LoRA K-tile 32 (A=G, B=BmT, ld=64).
// ---------------------------------------------------------------------------
__global__ __launch_bounds__(512, 2) void k_main(
    const u16* __restrict__ xbf, const u16* __restrict__ wbf,
    const u16* __restrict__ G, const u16* __restrict__ BmT,
    const float* __restrict__ bias, float* __restrict__ out)
{
  __shared__ u16 lds[65536];  // A bufs: [0,32768)  B bufs: [32768,65536)
  const int tid = threadIdx.x;
  const int w = tid >> 6, lane = tid & 63;
  const int fr = lane & 15, fg = lane >> 4;
  const int wr = w >> 2, wc = w & 3;

  // XCD-aware swizzle (256 blocks, 256%8==0 -> bijective)
  const int b0 = blockIdx.x;
  const int wg = (b0 & 7) * 32 + (b0 >> 3);
  const int mBase = (wg >> 3) * 256;   // 32 m-tiles
  const int nBase = (wg & 7) * 256;    //  8 n-tiles

  // staging addressing (linear LDS dest; swizzled global source col)
  const int rl = lane >> 3;                 // 0..7
  const int ce = ((lane & 7) ^ rl) << 3;    // source col elems (XOR swizzle)
  // ds_read addressing (same XOR involution)
  const int swz = (fr & 7) << 3;
  const int colk0 = (fg * 8) ^ swz;
  const int colk1 = (32 + fg * 8) ^ swz;
  const int aOff = (wr * 128 + fr) * 64;
  const int bOff = (wc * 64 + fr) * 64;

  f32x4 acc[8][4];
  const f32x4 zero = {0.f, 0.f, 0.f, 0.f};
#pragma unroll
  for (int mi = 0; mi < 8; ++mi)
#pragma unroll
    for (int nj = 0; nj < 4; ++nj) acc[mi][nj] = zero;

  // half codes: 0=A.lo 1=A.hi 2=B.lo 3=B.hi
  auto STAGE = [&](int s, int which) {
    if (s > 32) return;
    const bool isA = (which < 2);
    const int h = which & 1;
    const u16* src; int ld, k0;
    if (s < 32) { src = isA ? xbf : wbf; ld = 2048; k0 = s * 64; }
    else        { src = isA ? G   : BmT; ld = 64;   k0 = 0;      }
    const int rb = (isA ? mBase : nBase) + h * 128 + w * 8 + rl;
    u16* dst = lds + (isA ? 0 : 32768) + (s & 1) * 16384 + h * 8192 + w * 512;
    GLL16(src + rb * ld + k0 + ce, dst);                // rows rb..   (q=0)
    GLL16(src + (rb + 64) * ld + k0 + ce, dst + 4096);  // rows rb+64.. (q=1)
  };

#define MFMA_BURST(NJ)                                                        \
  __builtin_amdgcn_s_setprio(1);                                              \
  _Pragma("unroll")                                                           \
  for (int kk = 0; kk < 2; ++kk) {                                            \
    _Pragma("unroll")                                                         \
    for (int mi = 0; mi < 8; ++mi)                                            \
      acc[mi][NJ] = __builtin_amdgcn_mfma_f32_16x16x32_bf16(                  \
          a[mi][kk], bb[NJ][kk], acc[mi][NJ], 0, 0, 0);                       \
  }                                                                           \
  __builtin_amdgcn_s_setprio(0);

  // ---- prologue: tile0 all 4 halves + tile1 {A.lo, B.lo, A.hi}
  STAGE(0, 0); STAGE(0, 1); STAGE(0, 2); STAGE(0, 3);
  STAGE(1, 0); STAGE(1, 2); STAGE(1, 1);
  asm volatile("s_waitcnt vmcnt(6)" ::: "memory");
  __builtin_amdgcn_s_barrier();

  short8 a[8][2], bb[4][2];
#pragma unroll 1
  for (int t = 0; t < 33; ++t) {
    const u16* Ab = lds + (t & 1) * 16384;
    const u16* Bb = lds + 32768 + (t & 1) * 16384;
    // ---- phase 0
#pragma unroll
    for (int mi = 0; mi < 8; ++mi) {
      a[mi][0] = *(const short8*)(Ab + aOff + mi * 1024 + colk0);
      a[mi][1] = *(const short8*)(Ab + aOff + mi * 1024 + colk1);
    }
#pragma unroll
    for (int nj = 0; nj < 2; ++nj) {
      bb[nj][0] = *(const short8*)(Bb + bOff + nj * 1024 + colk0);
      bb[nj][1] = *(const short8*)(Bb + bOff + nj * 1024 + colk1);
    }
    STAGE(t + 1, 3);
    __builtin_amdgcn_s_barrier();
    asm volatile("s_waitcnt lgkmcnt(0)" ::: "memory");
    MFMA_BURST(0)
    __builtin_amdgcn_s_barrier();
    // ---- phase 1
#pragma unroll
    for (int nj = 2; nj < 4; ++nj) {
      bb[nj][0] = *(const short8*)(Bb + bOff + nj * 1024 + colk0);
      bb[nj][1] = *(const short8*)(Bb + bOff + nj * 1024 + colk1);
    }
    STAGE(t + 2, 0);
    __builtin_amdgcn_s_barrier();
    asm volatile("s_waitcnt lgkmcnt(0)" ::: "memory");
    MFMA_BURST(1)
    __builtin_amdgcn_s_barrier();
    // ---- phase 2
    STAGE(t + 2, 2);
    __builtin_amdgcn_s_barrier();
    MFMA_BURST(2)
    __builtin_amdgcn_s_barrier();
    // ---- phase 3
    STAGE(t + 2, 1);
    __builtin_amdgcn_s_barrier();
    MFMA_BURST(3)
    if (t < 31)       { asm volatile("s_waitcnt vmcnt(6)" ::: "memory"); }
    else if (t == 31) { asm volatile("s_waitcnt vmcnt(0)" ::: "memory"); }
    __builtin_amdgcn_s_barrier();
  }

  // ---- epilogue: bias add + store
#pragma unroll
  for (int nj = 0; nj < 4; ++nj) {
    const int n = nBase + wc * 64 + nj * 16 + fr;
    const float bv = bias[n];
#pragma unroll
    for (int mi = 0; mi < 8; ++mi) {
      const int m = mBase + wr * 128 + mi * 16 + fg * 4;
#pragma unroll
      for (int r = 0; r < 4; ++r)
        out[(m + r) * 2048 + n] = acc[mi][nj][r] + bv;
    }
  }
#undef MFMA_BURST
}

// ---------------------------------------------------------------------------
extern "C" void kernel_launch(void* const* d_in, const int* in_sizes, int n_in,
                              void* d_out, int out_size, void* d_ws, size_t ws_size,
                              hipStream_t stream) {
  const float* x  = (const float*)d_in[0];   // [4,2048,2048]
  const float* Wb = (const float*)d_in[1];   // [2048,2048]
  const float* bb = (const float*)d_in[2];   // [2048]
  const float* Wr = (const float*)d_in[3];   // [8,2048]
  const float* Aw = (const float*)d_in[4];   // [8,8,2048] == [64][2048]
  const float* Bw = (const float*)d_in[5];   // [8,2048,8]

  char* ws = (char*)d_ws;
  u16*   xbf  = (u16*)  (ws + 0);            // 33,554,432 B
  u16*   wbf  = (u16*)  (ws + 33554432);     //  8,388,608 B
  u16*   aabf = (u16*)  (ws + 41943040);     //    262,144 B
  u16*   bmt  = (u16*)  (ws + 42205184);     //    262,144 B
  float* lgt  = (float*)(ws + 42467328);     //    262,144 B
  u16*   G    = (u16*)  (ws + 42729472);     //  1,048,576 B
  // h-partials [8][8192][64] f32 live in d_out; fully consumed by k_topk
  // before k_main overwrites all of d_out. Same-stream ordering.
  float* P   = (float*)d_out;
  float* out = (float*)d_out;

  hipLaunchKernelGGL(k_conv_router, dim3(512),    dim3(512), 0, stream, x, Wr, xbf, lgt);
  hipLaunchKernelGGL(k_convert,     dim3(1064),   dim3(256), 0, stream, Wb, Aw, Bw, wbf, aabf, bmt);
  hipLaunchKernelGGL(k_hgemm,       dim3(32, 8),  dim3(256), 0, stream, xbf, aabf, P);
  hipLaunchKernelGGL(k_topk,        dim3(2048),   dim3(256), 0, stream, lgt, P, G);
  hipLaunchKernelGGL(k_main,        dim3(256),    dim3(512), 0, stream, xbf, wbf, G, bmt, bb, out);
}

// Round 4
// 122.253 us; speedup vs baseline: 1.7916x; 1.0387x over previous
//
#include <hip/hip_runtime.h>

typedef unsigned short u16;
typedef __attribute__((ext_vector_type(8))) short short8;
typedef __attribute__((ext_vector_type(4))) float f32x4;

#define GLL16(g, l) __builtin_amdgcn_global_load_lds(                         \
    (const __attribute__((address_space(1))) void*)(g),                        \
    (__attribute__((address_space(3))) void*)(l), 16, 0, 0)

__device__ __forceinline__ u16 f2bf(float f) {
  union { float f; unsigned u; } v; v.f = f;
  unsigned u = v.u;
  return (u16)((u + 0x7FFFu + ((u >> 16) & 1u)) >> 16);  // RNE
}

// ---------------------------------------------------------------------------
// Kernel A: convert x -> bf16, compute fp32 router logits (W_router in LDS).
// Chunk-interleaved (no large live array -> no scratch spill).
// ---------------------------------------------------------------------------
__global__ __launch_bounds__(512) void k_conv_router(
    const float* __restrict__ x, const float* __restrict__ Wr,
    u16* __restrict__ xbf, float* __restrict__ logits)
{
  __shared__ float wlds[16384];  // 8 x 2048 fp32 = 64 KB
  {
    const float4* src = (const float4*)Wr;
    float4* dst = (float4*)wlds;
    int t = threadIdx.x;
#pragma unroll
    for (int i = 0; i < 8; ++i) dst[t + i * 512] = src[t + i * 512];
  }
  __syncthreads();
  int wave = threadIdx.x >> 6, lane = threadIdx.x & 63;
  const float4* wv = (const float4*)wlds;
#pragma unroll 1
  for (int s = 0; s < 2; ++s) {
    int tok = blockIdx.x * 16 + wave * 2 + s;
    const float4* xrow = (const float4*)(x + tok * 2048);
    ushort4* orow = (ushort4*)(xbf + tok * 2048);
    float acc[8];
#pragma unroll
    for (int e = 0; e < 8; ++e) acc[e] = 0.f;
#pragma unroll 1
    for (int i = 0; i < 8; ++i) {
      float4 xv = xrow[lane + i * 64];
      ushort4 o;
      o.x = f2bf(xv.x); o.y = f2bf(xv.y);
      o.z = f2bf(xv.z); o.w = f2bf(xv.w);
      orow[lane + i * 64] = o;
#pragma unroll
      for (int e = 0; e < 8; ++e) {
        float4 b = wv[e * 512 + lane + i * 64];
        acc[e] += xv.x * b.x + xv.y * b.y + xv.z * b.z + xv.w * b.w;
      }
    }
#pragma unroll
    for (int e = 0; e < 8; ++e) {
      float v = acc[e];
#pragma unroll
      for (int off = 32; off > 0; off >>= 1) v += __shfl_xor(v, off, 64);
      acc[e] = v;
    }
    if (lane == 0) {
#pragma unroll
      for (int e = 0; e < 8; ++e) logits[tok * 8 + e] = acc[e];
    }
  }
}

// ---------------------------------------------------------------------------
// Kernel B: W_base->bf16, A_w->bf16, B_w -> BmatT [2048][64] bf16.
// ---------------------------------------------------------------------------
__global__ __launch_bounds__(256) void k_convert(
    const float* __restrict__ Wb, const float* __restrict__ Aw,
    const float* __restrict__ Bw,
    u16* __restrict__ wbf, u16* __restrict__ aabf, u16* __restrict__ bmt)
{
  int b = blockIdx.x, t = threadIdx.x;
  if (b < 1024) {
    int tid = b * 256 + t;
    const float4* src = (const float4*)Wb;
    ushort4* dst = (ushort4*)wbf;
#pragma unroll
    for (int i = 0; i < 4; ++i) {
      float4 v = src[tid + i * 262144];
      ushort4 o; o.x = f2bf(v.x); o.y = f2bf(v.y); o.z = f2bf(v.z); o.w = f2bf(v.w);
      dst[tid + i * 262144] = o;
    }
  } else if (b < 1056) {
    int tid = (b - 1024) * 256 + t;
    const float4* src = (const float4*)Aw;
    ushort4* dst = (ushort4*)aabf;
#pragma unroll
    for (int i = 0; i < 4; ++i) {
      float4 v = src[tid + i * 8192];
      ushort4 o; o.x = f2bf(v.x); o.y = f2bf(v.y); o.z = f2bf(v.z); o.w = f2bf(v.w);
      dst[tid + i * 8192] = o;
    }
  } else {
    int n = (b - 1056) * 256 + t;  // 0..2047
#pragma unroll
    for (int e = 0; e < 8; ++e) {
      const float4* src = (const float4*)(Bw + e * 16384 + n * 8);
      float4 v0 = src[0], v1 = src[1];
      ushort4 o0, o1;
      o0.x = f2bf(v0.x); o0.y = f2bf(v0.y); o0.z = f2bf(v0.z); o0.w = f2bf(v0.w);
      o1.x = f2bf(v1.x); o1.y = f2bf(v1.y); o1.z = f2bf(v1.z); o1.w = f2bf(v1.w);
      ushort4* dst = (ushort4*)(bmt + n * 64 + e * 8);
      dst[0] = o0; dst[1] = o1;
    }
  }
}

// ---------------------------------------------------------------------------
// Kernel C: h partials. h_all[m][64] = x_bf16 @ A_all^T, split-K (8 slices).
// ---------------------------------------------------------------------------
__global__ __launch_bounds__(256) void k_hgemm(
    const u16* __restrict__ xbf, const u16* __restrict__ aabf,
    float* __restrict__ P)
{
  __shared__ u16 As[256 * 64];
  __shared__ u16 Bs[64 * 64];
  int t = threadIdx.x, wave = t >> 6, lane = t & 63;
  int mBase = blockIdx.x * 256;
  int ks = blockIdx.y;
  int fr = lane & 15, fg = lane >> 4;
  int lrow = lane >> 3, lcol = (lane & 7) * 8;
  f32x4 zero = {0.f, 0.f, 0.f, 0.f};
  f32x4 acc[4][4];
#pragma unroll
  for (int i = 0; i < 4; ++i)
#pragma unroll
    for (int j = 0; j < 4; ++j) acc[i][j] = zero;
#pragma unroll 1
  for (int it = 0; it < 4; ++it) {
    int k0 = ks * 256 + it * 64;
    __syncthreads();
#pragma unroll
    for (int cc = 0; cc < 8; ++cc) {
      int c = wave * 8 + cc;
      GLL16(xbf + (mBase + c * 8 + lrow) * 2048 + k0 + lcol, &As[c * 512]);
    }
#pragma unroll
    for (int cc = 0; cc < 2; ++cc) {
      int c = wave * 2 + cc;
      GLL16(aabf + (c * 8 + lrow) * 2048 + k0 + lcol, &Bs[c * 512]);
    }
    __syncthreads();
#pragma unroll
    for (int kk = 0; kk < 2; ++kk) {
      short8 a[4], bfr[4];
#pragma unroll
      for (int i = 0; i < 4; ++i)
        a[i] = *(const short8*)&As[(wave * 64 + i * 16 + fr) * 64 + kk * 32 + fg * 8];
#pragma unroll
      for (int j = 0; j < 4; ++j)
        bfr[j] = *(const short8*)&Bs[(j * 16 + fr) * 64 + kk * 32 + fg * 8];
#pragma unroll
      for (int i = 0; i < 4; ++i)
#pragma unroll
        for (int j = 0; j < 4; ++j)
          acc[i][j] = __builtin_amdgcn_mfma_f32_16x16x32_bf16(a[i], bfr[j], acc[i][j], 0, 0, 0);
    }
  }
#pragma unroll
  for (int i = 0; i < 4; ++i)
#pragma unroll
    for (int j = 0; j < 4; ++j)
#pragma unroll
      for (int r = 0; r < 4; ++r) {
        int m = mBase + wave * 64 + i * 16 + fg * 4 + r;
        int n = j * 16 + fr;
        P[(ks * 8192 + m) * 64 + n] = acc[i][j][r];
      }
}

// ---------------------------------------------------------------------------
// Kernel D: per-token top-2 + softmax gates; reduce split-K partials; emit
// sparse gate-scaled G[8192][64] bf16.
// ---------------------------------------------------------------------------
__global__ __launch_bounds__(256) void k_topk(
    const float* __restrict__ logits, const float* __restrict__ P,
    u16* __restrict__ G)
{
  int t = threadIdx.x, wave = t >> 6, lane = t & 63;
  int tok = blockIdx.x * 4 + wave;
  const float* lg = logits + tok * 8;
  float la[8];
#pragma unroll
  for (int e = 0; e < 8; ++e) la[e] = lg[e];
  float v0 = la[0]; int i0 = 0;
#pragma unroll
  for (int e = 1; e < 8; ++e) { if (la[e] > v0) { v0 = la[e]; i0 = e; } }
  float v1 = -3.4e38f; int i1 = 0;
#pragma unroll
  for (int e = 0; e < 8; ++e) { if (e != i0 && la[e] > v1) { v1 = la[e]; i1 = e; } }
  float ex = expf(v1 - v0);
  float inv = 1.f / (1.f + ex);
  float gate0 = inv, gate1 = ex * inv;
  int e = lane >> 3;
  float h = 0.f;
#pragma unroll
  for (int ks = 0; ks < 8; ++ks) h += P[(ks * 8192 + tok) * 64 + lane];
  float g = (e == i0) ? gate0 : ((e == i1) ? gate1 : 0.f);
  G[tok * 64 + lane] = f2bf(2.0f * g * h);  // SCALE = alpha/r = 2
}

// ---------------------------------------------------------------------------
// Kernel E: main GEMM, 256x256 tile, BK=64, 8-phase schedule.
// K = 2048 (tiles 0..31) + virtual LoRA K-tile 32 (A=G, B=BmT, ld=64).
// M-quadrant bursts: phase p computes mi{2p,2p+1} x nj{0..3}; ds_read profile
// 12/4/4/4 per phase (balanced -> wave-stagger hides LDS drain under MFMA).
// Stage plan per tile t: (t+1).Alo@p0, (t+1).Ahi@p1 (opposite buffer),
// (t+2).Blo@p2, (t+2).Bhi@p3 (current B-buf; all B reads done by p0 barrier).
// vmcnt(4) per tile end: (t+1) A+B landed, (t+2).B (4 loads) in flight.
// ---------------------------------------------------------------------------
__global__ __launch_bounds__(512, 2) void k_main(
    const u16* __restrict__ xbf, const u16* __restrict__ wbf,
    const u16* __restrict__ G, const u16* __restrict__ BmT,
    const float* __restrict__ bias, float* __restrict__ out)
{
  __shared__ u16 lds[65536];  // A bufs: [0,32768)  B bufs: [32768,65536)
  const int tid = threadIdx.x;
  const int w = tid >> 6, lane = tid & 63;
  const int fr = lane & 15, fg = lane >> 4;
  const int wr = w >> 2, wc = w & 3;

  // XCD-aware swizzle (256 blocks, 256%8==0 -> bijective)
  const int b0 = blockIdx.x;
  const int wg = (b0 & 7) * 32 + (b0 >> 3);
  const int mBase = (wg >> 3) * 256;   // 32 m-tiles
  const int nBase = (wg & 7) * 256;    //  8 n-tiles

  // staging addressing (linear LDS dest; swizzled global source col)
  const int rl = lane >> 3;                 // 0..7
  const int ce = ((lane & 7) ^ rl) << 3;    // source col elems (XOR swizzle)
  // ds_read addressing (same XOR involution)
  const int swz = (fr & 7) << 3;
  const int colk0 = (fg * 8) ^ swz;
  const int colk1 = (32 + fg * 8) ^ swz;
  const int aOff = (wr * 128 + fr) * 64;
  const int bOff = (wc * 64 + fr) * 64;

  f32x4 acc[8][4];
  const f32x4 zero = {0.f, 0.f, 0.f, 0.f};
#pragma unroll
  for (int mi = 0; mi < 8; ++mi)
#pragma unroll
    for (int nj = 0; nj < 4; ++nj) acc[mi][nj] = zero;

  // half codes: 0=A.lo 1=A.hi 2=B.lo 3=B.hi
  auto STAGE = [&](int s, int which) {
    if (s > 32) return;
    const bool isA = (which < 2);
    const int h = which & 1;
    const u16* src; int ld, k0;
    if (s < 32) { src = isA ? xbf : wbf; ld = 2048; k0 = s * 64; }
    else        { src = isA ? G   : BmT; ld = 64;   k0 = 0;      }
    const int rb = (isA ? mBase : nBase) + h * 128 + w * 8 + rl;
    u16* dst = lds + (isA ? 0 : 32768) + (s & 1) * 16384 + h * 8192 + w * 512;
    GLL16(src + rb * ld + k0 + ce, dst);                // rows rb..   (q=0)
    GLL16(src + (rb + 64) * ld + k0 + ce, dst + 4096);  // rows rb+64.. (q=1)
  };

#define RDA(AV, MI0)                                                          \
  AV[0][0] = *(const short8*)(Ab + aOff + (MI0) * 1024 + colk0);              \
  AV[0][1] = *(const short8*)(Ab + aOff + (MI0) * 1024 + colk1);              \
  AV[1][0] = *(const short8*)(Ab + aOff + (MI0 + 1) * 1024 + colk0);          \
  AV[1][1] = *(const short8*)(Ab + aOff + (MI0 + 1) * 1024 + colk1);

#define MFMA_QUAD(AV, MI0)                                                    \
  __builtin_amdgcn_s_setprio(1);                                              \
  _Pragma("unroll")                                                           \
  for (int q = 0; q < 2; ++q)                                                 \
    _Pragma("unroll")                                                         \
    for (int nj = 0; nj < 4; ++nj)                                            \
      _Pragma("unroll")                                                       \
      for (int kk = 0; kk < 2; ++kk)                                          \
        acc[MI0 + q][nj] = __builtin_amdgcn_mfma_f32_16x16x32_bf16(           \
            AV[q][kk], bb[nj][kk], acc[MI0 + q][nj], 0, 0, 0);                \
  __builtin_amdgcn_s_setprio(0);

  // ---- prologue: tile0 all 4 halves + tile1 {B.lo, B.hi}
  STAGE(0, 0); STAGE(0, 1); STAGE(0, 2); STAGE(0, 3);
  STAGE(1, 2); STAGE(1, 3);
  asm volatile("s_waitcnt vmcnt(4)" ::: "memory");
  __builtin_amdgcn_s_barrier();

#pragma unroll 1
  for (int t = 0; t < 33; ++t) {
    const u16* Ab = lds + (t & 1) * 16384;
    const u16* Bb = lds + 32768 + (t & 1) * 16384;
    short8 bb[4][2];
    short8 a0[2][2], a1[2][2], a2[2][2], a3[2][2];
    // ---- phase 0: all B (8 reads) + A mi{0,1} (4 reads)
#pragma unroll
    for (int nj = 0; nj < 4; ++nj) {
      bb[nj][0] = *(const short8*)(Bb + bOff + nj * 1024 + colk0);
      bb[nj][1] = *(const short8*)(Bb + bOff + nj * 1024 + colk1);
    }
    RDA(a0, 0)
    STAGE(t + 1, 0);
    asm volatile("s_waitcnt lgkmcnt(8)" ::: "memory");
    __builtin_amdgcn_s_barrier();
    asm volatile("s_waitcnt lgkmcnt(0)" ::: "memory");
    MFMA_QUAD(a0, 0)
    __builtin_amdgcn_s_barrier();
    // ---- phase 1: A mi{2,3}
    RDA(a1, 2)
    STAGE(t + 1, 1);
    __builtin_amdgcn_s_barrier();
    asm volatile("s_waitcnt lgkmcnt(0)" ::: "memory");
    MFMA_QUAD(a1, 2)
    __builtin_amdgcn_s_barrier();
    // ---- phase 2: A mi{4,5}
    RDA(a2, 4)
    STAGE(t + 2, 2);
    __builtin_amdgcn_s_barrier();
    asm volatile("s_waitcnt lgkmcnt(0)" ::: "memory");
    MFMA_QUAD(a2, 4)
    __builtin_amdgcn_s_barrier();
    // ---- phase 3: A mi{6,7}
    RDA(a3, 6)
    STAGE(t + 2, 3);
    __builtin_amdgcn_s_barrier();
    asm volatile("s_waitcnt lgkmcnt(0)" ::: "memory");
    MFMA_QUAD(a3, 6)
    if (t < 31)       { asm volatile("s_waitcnt vmcnt(4)" ::: "memory"); }
    else if (t == 31) { asm volatile("s_waitcnt vmcnt(0)" ::: "memory"); }
    __builtin_amdgcn_s_barrier();
  }

  // ---- epilogue: bias add + store
#pragma unroll
  for (int nj = 0; nj < 4; ++nj) {
    const int n = nBase + wc * 64 + nj * 16 + fr;
    const float bv = bias[n];
#pragma unroll
    for (int mi = 0; mi < 8; ++mi) {
      const int m = mBase + wr * 128 + mi * 16 + fg * 4;
#pragma unroll
      for (int r = 0; r < 4; ++r)
        out[(m + r) * 2048 + n] = acc[mi][nj][r] + bv;
    }
  }
#undef MFMA_QUAD
#undef RDA
}

// ---------------------------------------------------------------------------
extern "C" void kernel_launch(void* const* d_in, const int* in_sizes, int n_in,
                              void* d_out, int out_size, void* d_ws, size_t ws_size,
                              hipStream_t stream) {
  const float* x  = (const float*)d_in[0];   // [4,2048,2048]
  const float* Wb = (const float*)d_in[1];   // [2048,2048]
  const float* bb = (const float*)d_in[2];   // [2048]
  const float* Wr = (const float*)d_in[3];   // [8,2048]
  const float* Aw = (const float*)d_in[4];   // [8,8,2048] == [64][2048]
  const float* Bw = (const float*)d_in[5];   // [8,2048,8]

  char* ws = (char*)d_ws;
  u16*   xbf  = (u16*)  (ws + 0);            // 33,554,432 B
  u16*   wbf  = (u16*)  (ws + 33554432);     //  8,388,608 B
  u16*   aabf = (u16*)  (ws + 41943040);     //    262,144 B
  u16*   bmt  = (u16*)  (ws + 42205184);     //    262,144 B
  float* lgt  = (float*)(ws + 42467328);     //    262,144 B
  u16*   G    = (u16*)  (ws + 42729472);     //  1,048,576 B
  // h-partials [8][8192][64] f32 live in d_out; fully consumed by k_topk
  // before k_main overwrites all of d_out. Same-stream ordering.
  float* P   = (float*)d_out;
  float* out = (float*)d_out;

  hipLaunchKernelGGL(k_conv_router, dim3(512),    dim3(512), 0, stream, x, Wr, xbf, lgt);
  hipLaunchKernelGGL(k_convert,     dim3(1064),   dim3(256), 0, stream, Wb, Aw, Bw, wbf, aabf, bmt);
  hipLaunchKernelGGL(k_hgemm,       dim3(32, 8),  dim3(256), 0, stream, xbf, aabf, P);
  hipLaunchKernelGGL(k_topk,        dim3(2048),   dim3(256), 0, stream, lgt, P, G);
  hipLaunchKernelGGL(k_main,        dim3(256),    dim3(512), 0, stream, xbf, wbf, G, bmt, bb, out);
}

// Round 5
// 116.618 us; speedup vs baseline: 1.8781x; 1.0483x over previous
//
#include <hip/hip_runtime.h>

typedef unsigned short u16;
typedef __attribute__((ext_vector_type(8))) short short8;
typedef __attribute__((ext_vector_type(4))) float f32x4;

#define GLL16(g, l) __builtin_amdgcn_global_load_lds(                         \
    (const __attribute__((address_space(1))) void*)(g),                        \
    (__attribute__((address_space(3))) void*)(l), 16, 0, 0)

__device__ __forceinline__ u16 f2bf(float f) {
  union { float f; unsigned u; } v; v.f = f;
  unsigned u = v.u;
  return (u16)((u + 0x7FFFu + ((u >> 16) & 1u)) >> 16);  // RNE
}

// ---------------------------------------------------------------------------
// Kernel A: convert x -> bf16, compute fp32 router logits (W_router in LDS).
// ---------------------------------------------------------------------------
__global__ __launch_bounds__(512) void k_conv_router(
    const float* __restrict__ x, const float* __restrict__ Wr,
    u16* __restrict__ xbf, float* __restrict__ logits)
{
  __shared__ float wlds[16384];  // 8 x 2048 fp32 = 64 KB
  {
    const float4* src = (const float4*)Wr;
    float4* dst = (float4*)wlds;
    int t = threadIdx.x;
#pragma unroll
    for (int i = 0; i < 8; ++i) dst[t + i * 512] = src[t + i * 512];
  }
  __syncthreads();
  int wave = threadIdx.x >> 6, lane = threadIdx.x & 63;
  const float4* wv = (const float4*)wlds;
#pragma unroll 1
  for (int s = 0; s < 2; ++s) {
    int tok = blockIdx.x * 16 + wave * 2 + s;
    const float4* xrow = (const float4*)(x + tok * 2048);
    ushort4* orow = (ushort4*)(xbf + tok * 2048);
    float acc[8];
#pragma unroll
    for (int e = 0; e < 8; ++e) acc[e] = 0.f;
#pragma unroll 1
    for (int i = 0; i < 8; ++i) {
      float4 xv = xrow[lane + i * 64];
      ushort4 o;
      o.x = f2bf(xv.x); o.y = f2bf(xv.y);
      o.z = f2bf(xv.z); o.w = f2bf(xv.w);
      orow[lane + i * 64] = o;
#pragma unroll
      for (int e = 0; e < 8; ++e) {
        float4 b = wv[e * 512 + lane + i * 64];
        acc[e] += xv.x * b.x + xv.y * b.y + xv.z * b.z + xv.w * b.w;
      }
    }
#pragma unroll
    for (int e = 0; e < 8; ++e) {
      float v = acc[e];
#pragma unroll
      for (int off = 32; off > 0; off >>= 1) v += __shfl_xor(v, off, 64);
      acc[e] = v;
    }
    if (lane == 0) {
#pragma unroll
      for (int e = 0; e < 8; ++e) logits[tok * 8 + e] = acc[e];
    }
  }
}

// ---------------------------------------------------------------------------
// Kernel B: W_base->bf16, A_w->bf16, B_w -> BmatT [2048][64] bf16.
// ---------------------------------------------------------------------------
__global__ __launch_bounds__(256) void k_convert(
    const float* __restrict__ Wb, const float* __restrict__ Aw,
    const float* __restrict__ Bw,
    u16* __restrict__ wbf, u16* __restrict__ aabf, u16* __restrict__ bmt)
{
  int b = blockIdx.x, t = threadIdx.x;
  if (b < 1024) {
    int tid = b * 256 + t;
    const float4* src = (const float4*)Wb;
    ushort4* dst = (ushort4*)wbf;
#pragma unroll
    for (int i = 0; i < 4; ++i) {
      float4 v = src[tid + i * 262144];
      ushort4 o; o.x = f2bf(v.x); o.y = f2bf(v.y); o.z = f2bf(v.z); o.w = f2bf(v.w);
      dst[tid + i * 262144] = o;
    }
  } else if (b < 1056) {
    int tid = (b - 1024) * 256 + t;
    const float4* src = (const float4*)Aw;
    ushort4* dst = (ushort4*)aabf;
#pragma unroll
    for (int i = 0; i < 4; ++i) {
      float4 v = src[tid + i * 8192];
      ushort4 o; o.x = f2bf(v.x); o.y = f2bf(v.y); o.z = f2bf(v.z); o.w = f2bf(v.w);
      dst[tid + i * 8192] = o;
    }
  } else {
    int n = (b - 1056) * 256 + t;  // 0..2047
#pragma unroll
    for (int e = 0; e < 8; ++e) {
      const float4* src = (const float4*)(Bw + e * 16384 + n * 8);
      float4 v0 = src[0], v1 = src[1];
      ushort4 o0, o1;
      o0.x = f2bf(v0.x); o0.y = f2bf(v0.y); o0.z = f2bf(v0.z); o0.w = f2bf(v0.w);
      o1.x = f2bf(v1.x); o1.y = f2bf(v1.y); o1.z = f2bf(v1.z); o1.w = f2bf(v1.w);
      ushort4* dst = (ushort4*)(bmt + n * 64 + e * 8);
      dst[0] = o0; dst[1] = o1;
    }
  }
}

// ---------------------------------------------------------------------------
// Kernel C: h partials. h_all[m][64] = x_bf16 @ A_all^T, split-K (8 slices).
// ---------------------------------------------------------------------------
__global__ __launch_bounds__(256) void k_hgemm(
    const u16* __restrict__ xbf, const u16* __restrict__ aabf,
    float* __restrict__ P)
{
  __shared__ u16 As[256 * 64];
  __shared__ u16 Bs[64 * 64];
  int t = threadIdx.x, wave = t >> 6, lane = t & 63;
  int mBase = blockIdx.x * 256;
  int ks = blockIdx.y;
  int fr = lane & 15, fg = lane >> 4;
  int lrow = lane >> 3, lcol = (lane & 7) * 8;
  f32x4 zero = {0.f, 0.f, 0.f, 0.f};
  f32x4 acc[4][4];
#pragma unroll
  for (int i = 0; i < 4; ++i)
#pragma unroll
    for (int j = 0; j < 4; ++j) acc[i][j] = zero;
#pragma unroll 1
  for (int it = 0; it < 4; ++it) {
    int k0 = ks * 256 + it * 64;
    __syncthreads();
#pragma unroll
    for (int cc = 0; cc < 8; ++cc) {
      int c = wave * 8 + cc;
      GLL16(xbf + (mBase + c * 8 + lrow) * 2048 + k0 + lcol, &As[c * 512]);
    }
#pragma unroll
    for (int cc = 0; cc < 2; ++cc) {
      int c = wave * 2 + cc;
      GLL16(aabf + (c * 8 + lrow) * 2048 + k0 + lcol, &Bs[c * 512]);
    }
    __syncthreads();
#pragma unroll
    for (int kk = 0; kk < 2; ++kk) {
      short8 a[4], bfr[4];
#pragma unroll
      for (int i = 0; i < 4; ++i)
        a[i] = *(const short8*)&As[(wave * 64 + i * 16 + fr) * 64 + kk * 32 + fg * 8];
#pragma unroll
      for (int j = 0; j < 4; ++j)
        bfr[j] = *(const short8*)&Bs[(j * 16 + fr) * 64 + kk * 32 + fg * 8];
#pragma unroll
      for (int i = 0; i < 4; ++i)
#pragma unroll
        for (int j = 0; j < 4; ++j)
          acc[i][j] = __builtin_amdgcn_mfma_f32_16x16x32_bf16(a[i], bfr[j], acc[i][j], 0, 0, 0);
    }
  }
#pragma unroll
  for (int i = 0; i < 4; ++i)
#pragma unroll
    for (int j = 0; j < 4; ++j)
#pragma unroll
      for (int r = 0; r < 4; ++r) {
        int m = mBase + wave * 64 + i * 16 + fg * 4 + r;
        int n = j * 16 + fr;
        P[(ks * 8192 + m) * 64 + n] = acc[i][j][r];
      }
}

// ---------------------------------------------------------------------------
// Kernel D: per-token top-2 + softmax gates; reduce split-K partials; emit
// sparse gate-scaled G[8192][64] bf16.
// ---------------------------------------------------------------------------
__global__ __launch_bounds__(256) void k_topk(
    const float* __restrict__ logits, const float* __restrict__ P,
    u16* __restrict__ G)
{
  int t = threadIdx.x, wave = t >> 6, lane = t & 63;
  int tok = blockIdx.x * 4 + wave;
  const float* lg = logits + tok * 8;
  float la[8];
#pragma unroll
  for (int e = 0; e < 8; ++e) la[e] = lg[e];
  float v0 = la[0]; int i0 = 0;
#pragma unroll
  for (int e = 1; e < 8; ++e) { if (la[e] > v0) { v0 = la[e]; i0 = e; } }
  float v1 = -3.4e38f; int i1 = 0;
#pragma unroll
  for (int e = 0; e < 8; ++e) { if (e != i0 && la[e] > v1) { v1 = la[e]; i1 = e; } }
  float ex = expf(v1 - v0);
  float inv = 1.f / (1.f + ex);
  float gate0 = inv, gate1 = ex * inv;
  int e = lane >> 3;
  float h = 0.f;
#pragma unroll
  for (int ks = 0; ks < 8; ++ks) h += P[(ks * 8192 + tok) * 64 + lane];
  float g = (e == i0) ? gate0 : ((e == i1) ? gate1 : 0.f);
  G[tok * 64 + lane] = f2bf(2.0f * g * h);  // SCALE = alpha/r = 2
}

// ---------------------------------------------------------------------------
// Kernel E: main GEMM, 256x256, BK=64, READ-AHEAD 4-phase pipeline.
// K = 2048 (tiles 0..31) + virtual LoRA K-tile 32 (A=G, B=BmT, ld=64).
// B(t) lives in REGISTERS during tile t (read as "Bnext" at t-1 p2/p3),
// freeing its LDS buffer for B(t+2) -> plain double-buffer suffices.
// A operands read one PHASE ahead (Aa/Ab reg ping-pong). Counted lgkmcnt
// waits retire only the prior batch, so the CU LDS queue never empties:
// drains hide under MFMA + barrier. 4 barriers/tile (was 8).
//   phase | MFMA (uses)      | ds_reads issued        | stage      | wait
//   p0    | mi01 (Aa,Bcur)   | A23->Ab   (4)          | A(t+1).lo  | lgkm(4)
//   p1    | mi23 (Ab,Bcur)   | A45->Aa   (4)          | A(t+1).hi  | lgkm(4); vmcnt(4) pre-bar
//   p2    | mi45 (Aa,Bcur)   | A67->Ab + Bn01 (8)     | B(t+2).lo  | lgkm(8); vmcnt(2) pre-bar (t=31: 0)
//   p3    | mi67 (Ab,Bcur)   | A01(t+1)->Aa + Bn23(8) | B(t+2).hi  | lgkm(8)
// vmcnt ledger (2 loads/half, issue order B(t+1)lo,hi | A(t+1)lo,hi |
// B(t+2)lo,hi): p1-end vmcnt(4) retires B(t+1) (read p2/p3); p2-end
// vmcnt(2) retires A(t+1) (read p3/next p0). Overwrite-safety: each stage
// issues >=1 barrier after victim buffer's reads were lgkm-retired.
// ---------------------------------------------------------------------------
__global__ __launch_bounds__(512, 2) void k_main(
    const u16* __restrict__ xbf, const u16* __restrict__ wbf,
    const u16* __restrict__ G, const u16* __restrict__ BmT,
    const float* __restrict__ bias, float* __restrict__ out)
{
  __shared__ u16 lds[65536];  // A bufs: [0,32768)  B bufs: [32768,65536)
  const int tid = threadIdx.x;
  const int w = tid >> 6, lane = tid & 63;
  const int fr = lane & 15, fg = lane >> 4;
  const int wr = w >> 2, wc = w & 3;

  // XCD-aware swizzle (256 blocks, 256%8==0 -> bijective)
  const int b0 = blockIdx.x;
  const int wg = (b0 & 7) * 32 + (b0 >> 3);
  const int mBase = (wg >> 3) * 256;   // 32 m-tiles
  const int nBase = (wg & 7) * 256;    //  8 n-tiles

  // staging addressing (linear LDS dest; swizzled global source col)
  const int rl = lane >> 3;                 // 0..7
  const int ce = ((lane & 7) ^ rl) << 3;    // source col elems (XOR swizzle)
  // ds_read addressing (same XOR involution)
  const int swz = (fr & 7) << 3;
  const int colk0 = (fg * 8) ^ swz;
  const int colk1 = (32 + fg * 8) ^ swz;
  const int aOff = (wr * 128 + fr) * 64;
  const int bOff = (wc * 64 + fr) * 64;

  f32x4 acc[8][4];
  const f32x4 zero = {0.f, 0.f, 0.f, 0.f};
#pragma unroll
  for (int mi = 0; mi < 8; ++mi)
#pragma unroll
    for (int nj = 0; nj < 4; ++nj) acc[mi][nj] = zero;

  // half codes: 0=A.lo 1=A.hi 2=B.lo 3=B.hi
  auto STAGE = [&](int s, int which) {
    if (s > 32) return;
    const bool isA = (which < 2);
    const int h = which & 1;
    const u16* src; int ld, k0;
    if (s < 32) { src = isA ? xbf : wbf; ld = 2048; k0 = s * 64; }
    else        { src = isA ? G   : BmT; ld = 64;   k0 = 0;      }
    const int rb = (isA ? mBase : nBase) + h * 128 + w * 8 + rl;
    u16* dst = lds + (isA ? 0 : 32768) + (s & 1) * 16384 + h * 8192 + w * 512;
    GLL16(src + rb * ld + k0 + ce, dst);                // rows rb..    (q=0)
    GLL16(src + (rb + 64) * ld + k0 + ce, dst + 4096);  // rows rb+64.. (q=1)
  };

  short8 Aa[2][2], Ab[2][2];   // A mi-pair ping-pong
  short8 Bx[4][2], By[4][2];   // B tile ping-pong (full tile in regs)

#define LGKM(N) asm volatile("s_waitcnt lgkmcnt(" #N ")" ::: "memory")
#define VMC(N)  asm volatile("s_waitcnt vmcnt(" #N ")" ::: "memory")
#define BAR()   __builtin_amdgcn_s_barrier()

#define RDA(DST, BUF, MI0)                                                    \
  DST[0][0] = *(const short8*)((BUF) + aOff + (MI0) * 1024 + colk0);          \
  DST[0][1] = *(const short8*)((BUF) + aOff + (MI0) * 1024 + colk1);          \
  DST[1][0] = *(const short8*)((BUF) + aOff + ((MI0) + 1) * 1024 + colk0);    \
  DST[1][1] = *(const short8*)((BUF) + aOff + ((MI0) + 1) * 1024 + colk1);

#define RDB(DST, BUF, NJ0)                                                    \
  DST[(NJ0)][0] = *(const short8*)((BUF) + bOff + (NJ0) * 1024 + colk0);      \
  DST[(NJ0)][1] = *(const short8*)((BUF) + bOff + (NJ0) * 1024 + colk1);      \
  DST[(NJ0)+1][0] = *(const short8*)((BUF) + bOff + ((NJ0)+1) * 1024 + colk0);\
  DST[(NJ0)+1][1] = *(const short8*)((BUF) + bOff + ((NJ0)+1) * 1024 + colk1);

#define MFMA16(AV, BV, MI0)                                                   \
  __builtin_amdgcn_s_setprio(1);                                              \
  _Pragma("unroll")                                                           \
  for (int kk = 0; kk < 2; ++kk)                                              \
    _Pragma("unroll")                                                         \
    for (int q = 0; q < 2; ++q)                                               \
      _Pragma("unroll")                                                       \
      for (int nj = 0; nj < 4; ++nj)                                          \
        acc[(MI0) + q][nj] = __builtin_amdgcn_mfma_f32_16x16x32_bf16(         \
            AV[q][kk], BV[nj][kk], acc[(MI0) + q][nj], 0, 0, 0);              \
  __builtin_amdgcn_s_setprio(0);

  // TILE(T, P=T&1 literal, BC=cur B regs, BN=next B regs)
#define TILE(T, P, BC, BN)                                                    \
  {                                                                           \
    const u16* Acur = lds + (P) * 16384;                                      \
    const u16* Anxt = lds + (1 - (P)) * 16384;                                \
    const u16* Bnxt = lds + 32768 + (1 - (P)) * 16384;                        \
    /* p0 */                                                                  \
    STAGE((T) + 1, 0);                                                        \
    RDA(Ab, Acur, 2)                                                          \
    LGKM(4);                                                                  \
    MFMA16(Aa, BC, 0)                                                         \
    BAR();                                                                    \
    /* p1 */                                                                  \
    STAGE((T) + 1, 1);                                                        \
    RDA(Aa, Acur, 4)                                                          \
    LGKM(4);                                                                  \
    MFMA16(Ab, BC, 2)                                                         \
    VMC(4);                                                                   \
    BAR();                                                                    \
    /* p2 */                                                                  \
    STAGE((T) + 2, 2);                                                        \
    RDA(Ab, Acur, 6)                                                          \
    RDB(BN, Bnxt, 0)                                                          \
    LGKM(8);                                                                  \
    MFMA16(Aa, BC, 4)                                                         \
    if ((T) == 31) { VMC(0); } else { VMC(2); }                               \
    BAR();                                                                    \
    /* p3 */                                                                  \
    STAGE((T) + 2, 3);                                                        \
    RDA(Aa, Anxt, 0)                                                          \
    RDB(BN, Bnxt, 2)                                                          \
    LGKM(8);                                                                  \
    MFMA16(Ab, BC, 6)                                                         \
    BAR();                                                                    \
  }

  // ---- prologue: stage A0,B0,B1 (12 loads); land A0,B0; read B0 + A01(0)
  STAGE(0, 0); STAGE(0, 1); STAGE(0, 2); STAGE(0, 3);
  STAGE(1, 2); STAGE(1, 3);
  VMC(4);
  BAR();
  {
    const u16* Bb0 = lds + 32768;
    RDB(Bx, Bb0, 0)
    RDB(Bx, Bb0, 2)
    RDA(Aa, lds, 0)
  }

#pragma unroll 1
  for (int tt = 0; tt < 16; ++tt) {
    const int t0 = tt * 2;
    TILE(t0, 0, Bx, By)
    TILE(t0 + 1, 1, By, Bx)
  }

  // ---- tile 32 (LoRA): no stages, no barriers, Bcur = Bx (read at t=31 p3)
  {
    const u16* Acur = lds;  // 32&1 == 0
    RDA(Ab, Acur, 2)
    LGKM(4);
    MFMA16(Aa, Bx, 0)
    RDA(Aa, Acur, 4)
    LGKM(4);
    MFMA16(Ab, Bx, 2)
    RDA(Ab, Acur, 6)
    LGKM(4);
    MFMA16(Aa, Bx, 4)
    LGKM(0);
    MFMA16(Ab, Bx, 6)
  }

  // ---- epilogue: bias add + store
#pragma unroll
  for (int nj = 0; nj < 4; ++nj) {
    const int n = nBase + wc * 64 + nj * 16 + fr;
    const float bv = bias[n];
#pragma unroll
    for (int mi = 0; mi < 8; ++mi) {
      const int m = mBase + wr * 128 + mi * 16 + fg * 4;
#pragma unroll
      for (int r = 0; r < 4; ++r)
        out[(m + r) * 2048 + n] = acc[mi][nj][r] + bv;
    }
  }
#undef TILE
#undef MFMA16
#undef RDB
#undef RDA
#undef BAR
#undef VMC
#undef LGKM
}

// ---------------------------------------------------------------------------
extern "C" void kernel_launch(void* const* d_in, const int* in_sizes, int n_in,
                              void* d_out, int out_size, void* d_ws, size_t ws_size,
                              hipStream_t stream) {
  const float* x  = (const float*)d_in[0];   // [4,2048,2048]
  const float* Wb = (const float*)d_in[1];   // [2048,2048]
  const float* bb = (const float*)d_in[2];   // [2048]
  const float* Wr = (const float*)d_in[3];   // [8,2048]
  const float* Aw = (const float*)d_in[4];   // [8,8,2048] == [64][2048]
  const float* Bw = (const float*)d_in[5];   // [8,2048,8]

  char* ws = (char*)d_ws;
  u16*   xbf  = (u16*)  (ws + 0);            // 33,554,432 B
  u16*   wbf  = (u16*)  (ws + 33554432);     //  8,388,608 B
  u16*   aabf = (u16*)  (ws + 41943040);     //    262,144 B
  u16*   bmt  = (u16*)  (ws + 42205184);     //    262,144 B
  float* lgt  = (float*)(ws + 42467328);     //    262,144 B
  u16*   G    = (u16*)  (ws + 42729472);     //  1,048,576 B
  // h-partials [8][8192][64] f32 live in d_out; fully consumed by k_topk
  // before k_main overwrites all of d_out. Same-stream ordering.
  float* P   = (float*)d_out;
  float* out = (float*)d_out;

  hipLaunchKernelGGL(k_conv_router, dim3(512),    dim3(512), 0, stream, x, Wr, xbf, lgt);
  hipLaunchKernelGGL(k_convert,     dim3(1064),   dim3(256), 0, stream, Wb, Aw, Bw, wbf, aabf, bmt);
  hipLaunchKernelGGL(k_hgemm,       dim3(32, 8),  dim3(256), 0, stream, xbf, aabf, P);
  hipLaunchKernelGGL(k_topk,        dim3(2048),   dim3(256), 0, stream, lgt, P, G);
  hipLaunchKernelGGL(k_main,        dim3(256),    dim3(512), 0, stream, xbf, wbf, G, bmt, bb, out);
}